// Round 8
// baseline (105.153 us; speedup 1.0000x reference)
//
#include <hip/hip_runtime.h>

// WaveletFilterNet fused: haar_forward -> per-channel filter -> haar_inverse
// x: (16,1,2048,2048) fp32, filt: (1,3,1024,1024) fp32, out: (16,1,2048,2048) fp32
//
// Per 2x2 input block {A,B,C,D}:
//   P=A+B+C+D, Q=A-B-C+D (HH), R=A+B-C-D (HL), S=A-B+C-D (LH)
// filt ch0 scales HH, ch1 scales HL, ch2 scales LH (reference returns LL,HH,HL,LH).
//   out[2i  ,2j]=.25(P+q+r+s)  out[2i  ,2j+1]=.25(P-q+r-s)
//   out[2i+1,2j]=.25(P+q-r-s)  out[2i+1,2j+1]=.25(P-q-r+s)
//
// R7 = R6 + two images per thread (b and b+8): filter loaded once per thread
// and reused across both images; 4 independent packed f32x4 x-loads in
// flight (ILP up), filter load instrs halved, blocks 32768 -> 16384.
// Every global access stays 64 lanes x 16B contiguous.

#define B_    16
#define H_    2048
#define W_    2048
#define H2_   1024
#define W2_   1024

typedef float f32x4 __attribute__((ext_vector_type(4)));
typedef float f32x2 __attribute__((ext_vector_type(2)));

struct Quad { float o00, o01, o10, o11; };

__device__ __forceinline__ Quad haar_block(float A, float Bv, float C, float D,
                                           float f0, float f1, float f2)
{
    const float P = A + Bv + C + D;
    const float q = f0 * (A - Bv - C + D);   // HH
    const float r = f1 * (A + Bv - C - D);   // HL
    const float s = f2 * (A - Bv + C - D);   // LH
    Quad o;
    o.o00 = 0.25f * (P + q + r + s);
    o.o01 = 0.25f * (P - q + r - s);
    o.o10 = 0.25f * (P + q - r - s);
    o.o11 = 0.25f * (P - q - r + s);
    return o;
}

__global__ __launch_bounds__(256) void wavelet_fused_kernel(
    const float* __restrict__ x,
    const float* __restrict__ filt,
    float* __restrict__ out)
{
    // grid = 16384; bid = (spatial_chunk << 3) | batch_pair.
    // Each WG covers half a row-pair of TWO images (b and b+8).
    const unsigned bid = blockIdx.x;
    const unsigned bp  = bid & 7u;            // batch pair: images bp, bp+8
    const unsigned sp  = bid >> 3;            // [0, 2048)
    const unsigned i   = sp >> 1;             // block-row in [0,1024)
    const unsigned jh  = sp & 1u;             // which half-row

    const unsigned jt = jh * 256u + threadIdx.x;   // float4 index in row, [0,512)

    const long long off0 = (((long long)bp * H_) + 2 * i) * W_ + (long long)jt * 4;
    const long long off1 = off0 + (long long)8 * H_ * W_;   // image bp+8

    // 4 independent packed loads (each: 64 lanes x 16B contiguous)
    const f32x4 t0 = *reinterpret_cast<const f32x4*>(x + off0);
    const f32x4 c0 = *reinterpret_cast<const f32x4*>(x + off0 + W_);
    const f32x4 t1 = *reinterpret_cast<const f32x4*>(x + off1);
    const f32x4 c1 = *reinterpret_cast<const f32x4*>(x + off1 + W_);

    const long long fOff = (long long)i * W2_ + (long long)jt * 2;
    const f32x2 f0 = *reinterpret_cast<const f32x2*>(filt + 0 * (H2_ * W2_) + fOff); // HH
    const f32x2 f1 = *reinterpret_cast<const f32x2*>(filt + 1 * (H2_ * W2_) + fOff); // HL
    const f32x2 f2 = *reinterpret_cast<const f32x2*>(filt + 2 * (H2_ * W2_) + fOff); // LH

    const Quad qa0 = haar_block(t0.x, t0.y, c0.x, c0.y, f0.x, f1.x, f2.x);
    const Quad qa1 = haar_block(t0.z, t0.w, c0.z, c0.w, f0.y, f1.y, f2.y);
    const Quad qb0 = haar_block(t1.x, t1.y, c1.x, c1.y, f0.x, f1.x, f2.x);
    const Quad qb1 = haar_block(t1.z, t1.w, c1.z, c1.w, f0.y, f1.y, f2.y);

    f32x4 oa0, oa1, ob0, ob1;
    oa0.x = qa0.o00; oa0.y = qa0.o01; oa0.z = qa1.o00; oa0.w = qa1.o01;
    oa1.x = qa0.o10; oa1.y = qa0.o11; oa1.z = qa1.o10; oa1.w = qa1.o11;
    ob0.x = qb0.o00; ob0.y = qb0.o01; ob0.z = qb1.o00; ob0.w = qb1.o01;
    ob1.x = qb0.o10; ob1.y = qb0.o11; ob1.z = qb1.o10; ob1.w = qb1.o11;

    *reinterpret_cast<f32x4*>(out + off0)      = oa0;
    *reinterpret_cast<f32x4*>(out + off0 + W_) = oa1;
    *reinterpret_cast<f32x4*>(out + off1)      = ob0;
    *reinterpret_cast<f32x4*>(out + off1 + W_) = ob1;
}

extern "C" void kernel_launch(void* const* d_in, const int* in_sizes, int n_in,
                              void* d_out, int out_size, void* d_ws, size_t ws_size,
                              hipStream_t stream) {
    const float* x    = (const float*)d_in[0];
    const float* filt = (const float*)d_in[1];
    float* out        = (float*)d_out;

    const unsigned total_threads = (B_ / 2) * H2_ * (W_ / 4); // 8*1024*512 = 4,194,304
    const unsigned block = 256;
    const unsigned grid = total_threads / block;              // 16384
    wavelet_fused_kernel<<<grid, block, 0, stream>>>(x, filt, out);
}

// Round 9
// 95.554 us; speedup vs baseline: 1.1004x; 1.1004x over previous
//
#include <hip/hip_runtime.h>

// WaveletFilterNet fused: haar_forward -> per-channel filter -> haar_inverse
// x: (16,1,2048,2048) fp32, filt: (1,3,1024,1024) fp32, out: (16,1,2048,2048) fp32
//
// Per 2x2 input block {A,B,C,D}:
//   P=A+B+C+D, Q=A-B-C+D (HH), R=A+B-C-D (HL), S=A-B+C-D (LH)
// filt ch0 scales HH, ch1 scales HL, ch2 scales LH (reference returns LL,HH,HL,LH).
//   out[2i  ,2j]=.25(P+q+r+s)  out[2i  ,2j+1]=.25(P-q+r-s)
//   out[2i+1,2j]=.25(P+q-r-s)  out[2i+1,2j+1]=.25(P-q-r+s)
//
// R8 = R6 (best: 101.2us) + nontemporal STORES only. Out-stream is
// write-once/never-read; NT keeps it from evicting filter (12.6MB, reused
// 16x) and x-prefetch from L2/L3. Loads stay cached. Stores are full-line
// (wave = 1KB aligned contiguous) so no RMW. R7's 2-images/thread reverted
// (TLP halving regressed 101.2 -> 105.2).

#define B_    16
#define H_    2048
#define W_    2048
#define H2_   1024
#define W2_   1024

typedef float f32x4 __attribute__((ext_vector_type(4)));
typedef float f32x2 __attribute__((ext_vector_type(2)));

struct Quad { float o00, o01, o10, o11; };

__device__ __forceinline__ Quad haar_block(float A, float Bv, float C, float D,
                                           float f0, float f1, float f2)
{
    const float P = A + Bv + C + D;
    const float q = f0 * (A - Bv - C + D);   // HH
    const float r = f1 * (A + Bv - C - D);   // HL
    const float s = f2 * (A - Bv + C - D);   // LH
    Quad o;
    o.o00 = 0.25f * (P + q + r + s);
    o.o01 = 0.25f * (P - q + r - s);
    o.o10 = 0.25f * (P + q - r - s);
    o.o11 = 0.25f * (P - q - r + s);
    return o;
}

__global__ __launch_bounds__(256) void wavelet_fused_kernel(
    const float* __restrict__ x,
    const float* __restrict__ filt,
    float* __restrict__ out)
{
    // grid = 32768; bid = (spatial_chunk << 4) | batch. Each WG covers half a
    // row-pair: 256 threads x 1 float4 = 1024 input cols.
    const unsigned bid = blockIdx.x;
    const unsigned b   = bid & 15u;
    const unsigned sp  = bid >> 4;            // [0, 2048)
    const unsigned i   = sp >> 1;             // block-row in [0,1024)
    const unsigned jh  = sp & 1u;             // which half-row

    const unsigned jt = jh * 256u + threadIdx.x;   // float4 index in row, [0,512)

    const long long inOff = (((long long)b * H_) + 2 * i) * W_ + (long long)jt * 4;

    const f32x4 t0 = *reinterpret_cast<const f32x4*>(x + inOff);
    const f32x4 c0 = *reinterpret_cast<const f32x4*>(x + inOff + W_);

    const long long fOff = (long long)i * W2_ + (long long)jt * 2;
    const f32x2 f0 = *reinterpret_cast<const f32x2*>(filt + 0 * (H2_ * W2_) + fOff); // HH
    const f32x2 f1 = *reinterpret_cast<const f32x2*>(filt + 1 * (H2_ * W2_) + fOff); // HL
    const f32x2 f2 = *reinterpret_cast<const f32x2*>(filt + 2 * (H2_ * W2_) + fOff); // LH

    const Quad q0 = haar_block(t0.x, t0.y, c0.x, c0.y, f0.x, f1.x, f2.x);
    const Quad q1 = haar_block(t0.z, t0.w, c0.z, c0.w, f0.y, f1.y, f2.y);

    f32x4 o0, o1;
    o0.x = q0.o00; o0.y = q0.o01; o0.z = q1.o00; o0.w = q1.o01;
    o1.x = q0.o10; o1.y = q0.o11; o1.z = q1.o10; o1.w = q1.o11;

    __builtin_nontemporal_store(o0, reinterpret_cast<f32x4*>(out + inOff));
    __builtin_nontemporal_store(o1, reinterpret_cast<f32x4*>(out + inOff + W_));
}

extern "C" void kernel_launch(void* const* d_in, const int* in_sizes, int n_in,
                              void* d_out, int out_size, void* d_ws, size_t ws_size,
                              hipStream_t stream) {
    const float* x    = (const float*)d_in[0];
    const float* filt = (const float*)d_in[1];
    float* out        = (float*)d_out;

    const unsigned total_threads = B_ * H2_ * (W_ / 4); // 16*1024*512 = 8,388,608
    const unsigned block = 256;
    const unsigned grid = total_threads / block;        // 32768
    wavelet_fused_kernel<<<grid, block, 0, stream>>>(x, filt, out);
}